// Round 17
// baseline (547.778 us; speedup 1.0000x reference)
//
#include <hip/hip_runtime.h>
#include <hip/hip_bf16.h>
#include <hip/hip_fp16.h>

typedef __attribute__((ext_vector_type(8))) short bf16x8;
typedef __attribute__((ext_vector_type(4))) float f32x4;
typedef unsigned short u16;

static __device__ __forceinline__ u16 f2bf(float f) {
    union { float f; unsigned int i; } c; c.f = f;
    unsigned int r = c.i + 0x7fffu + ((c.i >> 16) & 1u);
    return (u16)(r >> 16);
}
static __device__ __forceinline__ float bf2f(u16 u) {
    union { unsigned int i; float f; } c; c.i = ((unsigned int)u) << 16; return c.f;
}
static __device__ __forceinline__ u16 f2h(float f) {
    __half h = __float2half(f);
    return *(u16*)&h;
}
static __device__ __forceinline__ float h2f(u16 u) {
    __half h = *(__half*)&u;
    return __half2float(h);
}

#define AS1(p) ((const __attribute__((address_space(1))) void*)(p))
#define AS3(p) ((__attribute__((address_space(3))) void*)(p))
static __device__ __forceinline__ void glds16(const void* g, void* l) {
    __builtin_amdgcn_global_load_lds(AS1(g), AS3(l), 16, 0, 0);
}

// XCD-coherent swizzle: 1D grid, nwg%8==0, nwg/8 == blocks per batch.
static __device__ __forceinline__ void xcdmap(int nwg, int nx, int& x, int& y, int& z) {
    const int lin = blockIdx.x;
    const int per = nwg >> 3;
    const int swz = (lin & 7) * per + (lin >> 3);
    z = swz / per;                 // == lin & 7
    const int rem = swz - z * per;
    x = rem % nx;
    y = rem / nx;
}

// ---------------- workspace layout (byte offsets) ----------------
static constexpr long B_EMB  = 0;                       // bf16 embB [32000,256]
static constexpr long B_SF   = 16777216;                // fp16 scores [8,1024,1024]
static constexpr long B_SXP  = B_SF   + 33554432;       // bf16 [Xp|S]   [8,1024,1280]
static constexpr long B_STXP = B_SXP  + 20971520;       // bf16 [Xp|S^T] [8,1024,1280]
static constexpr long B_QH   = B_STXP + 20971520;       // bf16 [Q|H] [8,1024,512]
static constexpr long B_KVQ  = B_QH   + 8388608;        // bf16 [K|V|Q] [8,1024,768]
static constexpr long B_BQ   = B_KVQ  + 12582912;       // bf16 [Wq|K^T] [8,256,1280]
static constexpr long B_BKV  = B_BQ   + 5242880;        // bf16 [Wk|Q^T ; Wv|H^T] [8,512,1280]
static constexpr long B_VT   = B_BKV  + 10485760;       // bf16 V^T [8,256,1024]
static constexpr long B_W3T  = B_VT   + 4194304;        // bf16 [Wk^T|Wv^T|Wq^T] [256,768]
static constexpr long B_XRB  = B_W3T  + 393216;         // bf16 Xm masked rows [512,256]
static constexpr long B_PE   = B_XRB  + 262144;         // fp32 PE [1024,256]
static constexpr long B_PAD  = B_PE   + 1048576;        // int pad flags
static constexpr long B_MSK  = B_PAD  + 32768;          // int mask flags
static constexpr long B_DH   = B_MSK  + 32768;          // bf16 dH [8,1024,256]

static constexpr long sSX  = 1024L * 1280;
static constexpr long sQH  = 1024L * 512;
static constexpr long sKVQ = 1024L * 768;
static constexpr long sBQ  = 256L * 1280;
static constexpr long sBKV = 512L * 1280;
static constexpr long sVT  = 256L * 1024;
static constexpr long sS2  = 1024L * 1024;
static constexpr long sDH  = 1024L * 256;

// ---------------- setup: PE + flags + weight converts + emb->bf16 in ONE launch ----------------
__global__ __launch_bounds__(256) void k_setup(float* __restrict__ PE, const int* __restrict__ ix,
                                               int* __restrict__ padf, int* __restrict__ maskf,
                                               const float* __restrict__ Wq, const float* __restrict__ Wk,
                                               const float* __restrict__ Wv, const float* __restrict__ emb,
                                               char* __restrict__ base) {
    __shared__ u16 tile[32][33];
    const int bid = blockIdx.x;
    if (bid < 512) {
        int g = bid * 256 + threadIdx.x;
        int p = g >> 7, j = g & 127;
        float di   = (float)j * (1.0f / 128.0f);
        float freq = powf(10000.0f, -di);
        float ang  = (float)p * freq;
        PE[(long)p * 256 + j]       = sinf(ang);
        PE[(long)p * 256 + j + 128] = cosf(ang);
        return;
    }
    if (bid < 544) {
        int g = (bid - 512) * 256 + threadIdx.x;
        int tok = ix[g];
        padf[g]  = (tok == 0) ? 1 : 0;
        maskf[g] = (tok == 1) ? 1 : 0;
        return;
    }
    if (bid < 2080) {
        const int idx = bid - 544;
        const int bz = idx >> 6, rem = idx & 63;
        const int bx = rem >> 3, by = rem & 7;
        const int ws = bz >> 3, rb8 = bz & 7;
        const float* W; u16 *rep, *T; long repStride;
        if (ws == 0)      { W = Wk; rep = (u16*)(base + B_BKV);               T = (u16*)(base + B_W3T);       repStride = sBKV; }
        else if (ws == 1) { W = Wv; rep = (u16*)(base + B_BKV) + 256L * 1280; T = (u16*)(base + B_W3T) + 256; repStride = sBKV; }
        else              { W = Wq; rep = (u16*)(base + B_BQ);                T = (u16*)(base + B_W3T) + 512; repStride = sBQ; }
        rep += (long)rb8 * repStride;
        const int tx = threadIdx.x & 31, ty = threadIdx.x >> 5;
#pragma unroll
        for (int rr = 0; rr < 32; rr += 8) {
            int r = bx * 32 + ty + rr, c = by * 32 + tx;
            u16 u = f2bf(W[(long)r * 256 + c]);
            rep[(long)r * 1280 + c] = u;
            if (rb8 == 0) tile[ty + rr][tx] = u;
        }
        if (rb8 == 0) {
            __syncthreads();
#pragma unroll
            for (int rr = 0; rr < 32; rr += 8)
                T[(long)(by * 32 + ty + rr) * 768 + bx * 32 + tx] = tile[tx][ty + rr];
        }
        return;
    }
    // emb -> bf16: bid in [2080, 10080)
    long e = ((long)(bid - 2080) * 256 + threadIdx.x) * 4;
    float4 v = *(const float4*)(emb + e);
    ushort4 o;
    o.x = f2bf(v.x); o.y = f2bf(v.y); o.z = f2bf(v.z); o.w = f2bf(v.w);
    *(ushort4*)((u16*)(base + B_EMB) + e) = o;
}

// ---------------- fused embed + Xp ----------------
__global__ __launch_bounds__(256) void k_embx(const int* __restrict__ ix, const float* __restrict__ emb,
                                              const float* __restrict__ PE,
                                              u16* __restrict__ SXp, u16* __restrict__ STXp) {
    int g = blockIdx.x * 256 + threadIdx.x;
    long e = (long)g * 4;
    long bn = e >> 8;
    int i = (int)(bn & 1023), c = (int)(e & 255);
    int tok = ix[bn];
    float4 v;
    if (tok == 1) v = make_float4(0.f, 0.f, 0.f, 0.f);
    else          v = *(const float4*)(emb + (long)tok * 256 + c);
    float4 p = *(const float4*)(PE + (long)i * 256 + c);
    ushort4 o;
    o.x = f2bf(v.x + p.x); o.y = f2bf(v.y + p.y);
    o.z = f2bf(v.z + p.z); o.w = f2bf(v.w + p.w);
    long oo = bn * 1280 + c;
    *(ushort4*)(SXp + oo)  = o;
    *(ushort4*)(STXp + oo) = o;
}

// ---------------- merged Q1 + KV1 update (one 1D launch, XCD-swizzled: batch z -> XCD z) ----------------
__global__ __launch_bounds__(256)
void k_gupd(const u16* __restrict__ SXp, const u16* __restrict__ STXp,
            u16* __restrict__ BQ, u16* __restrict__ BKV,
            u16* __restrict__ QHb, u16* __restrict__ KVQ, u16* __restrict__ VTb, int K) {
    int xb, y, z;
    xcdmap(768, 8, xb, y, z);
    const int i0 = xb * 128;
    const u16 *A, *B;
    u16 *outR, *T;
    int j0, ldR, ldT, jloc;
    if (y < 4) {
        j0 = y << 6;
        A = SXp + (long)z * sSX;  B = BQ + (long)z * sBQ;
        outR  = QHb + (long)z * sQH;          ldR = 512;
        T = BKV + 256 + (long)z * sBKV;       ldT = 1280; jloc = j0;
    } else {
        j0 = (y - 4) << 6;
        A = STXp + (long)z * sSX;  B = BKV + (long)z * sBKV;
        outR  = KVQ + (long)z * sKVQ;         ldR = 768;
        if (j0 < 256) { T = BQ + 256 + (long)z * sBQ; ldT = 1280; jloc = j0; }
        else          { T = VTb + (long)z * sVT;      ldT = 1024; jloc = j0 - 256; }
    }

    __shared__ u16 As[128 * 32];
    __shared__ u16 Bs[64 * 32];
    __shared__ u16 Tt[64][136];
    const int t = threadIdx.x, w = t >> 6, l = t & 63;
    const int wr = (w >> 1) << 6, wc = (w & 1) << 5;
    const int lr = l & 15, lk = (l >> 4) << 3;
    f32x4 acc[4][2] = {};

    const u16* ga = A + (long)(i0 + (t >> 2)) * 1280 + ((t & 3) << 3);
    const u16* gb = B + (long)(j0 + (t >> 2)) * 1280 + ((t & 3) << 3);
    const long a64 = 1280L << 6;
    char* lA = (char*)As + (w << 10);
    char* lB = (char*)Bs + (w << 10);

    for (int k0 = 0; k0 < K; k0 += 32) {
        glds16(ga + k0,       lA);
        glds16(ga + k0 + a64, lA + 4096);
        glds16(gb + k0,       lB);
        __syncthreads();
        bf16x8 af[4], bb[2];
#pragma unroll
        for (int m = 0; m < 4; ++m)
            af[m] = *(const bf16x8*)(As + ((wr + (m << 4) + lr) << 5) + lk);
#pragma unroll
        for (int n = 0; n < 2; ++n)
            bb[n] = *(const bf16x8*)(Bs + ((wc + (n << 4) + lr) << 5) + lk);
#pragma unroll
        for (int m = 0; m < 4; ++m)
#pragma unroll
            for (int n = 0; n < 2; ++n)
                acc[m][n] = __builtin_amdgcn_mfma_f32_16x16x32_bf16(af[m], bb[n], acc[m][n], 0, 0, 0);
        __syncthreads();
    }

    const int rb  = wr + ((l >> 4) << 2);
    const int cbl = wc + lr;
#pragma unroll
    for (int m = 0; m < 4; ++m)
#pragma unroll
        for (int n = 0; n < 2; ++n)
#pragma unroll
            for (int j = 0; j < 4; ++j) {
                u16 u = f2bf(acc[m][n][j]);
                int rl = rb + (m << 4) + j;
                int cl = cbl + (n << 4);
                outR[(long)(i0 + rl) * ldR + j0 + cl] = u;
                Tt[cl][rl] = u;
            }
    __syncthreads();
#pragma unroll
    for (int p = 0; p < 4; ++p) {
        int id = p * 256 + t;
        int jj = id >> 4, ch = id & 15;
        uint4 v = *(const uint4*)&Tt[jj][ch << 3];
        *(uint4*)(T + (long)(jloc + jj) * ldT + i0 + (ch << 3)) = v;
    }
}

// ---------------- H-update: H = S1 V (K=960) + dH emission ----------------
__global__ __launch_bounds__(256)
void k_gbh(const u16* __restrict__ SXp, const u16* __restrict__ VTb,
           u16* __restrict__ QHb, u16* __restrict__ BKV, u16* __restrict__ DH, int it0) {
    int xb, yb, z;
    xcdmap(256, 8, xb, yb, z);
    const u16* A = SXp + 256 + (long)z * sSX;
    const u16* B = VTb + (long)z * sVT;
    u16* outR = QHb + 256 + (long)z * sQH;
    u16* T    = BKV + 256L * 1280 + 256 + (long)z * sBKV;
    u16* dh   = DH + (long)z * sDH;
    const int i0 = xb * 128, j0 = yb * 64;

    __shared__ u16 As[128 * 32];
    __shared__ u16 Bs[64 * 32];
    __shared__ u16 Tt[64][136];
    const int t = threadIdx.x, w = t >> 6, l = t & 63;
    const int wr = (w >> 1) << 6, wc = (w & 1) << 5;
    const int lr = l & 15, lk = (l >> 4) << 3;
    f32x4 acc[4][2] = {};

    const u16* ga = A + (long)(i0 + (t >> 2)) * 1280 + ((t & 3) << 3);
    const u16* gb = B + (long)(j0 + (t >> 2)) * 1024 + ((t & 3) << 3);
    const long a64 = 1280L << 6;
    char* lA = (char*)As + (w << 10);
    char* lB = (char*)Bs + (w << 10);

    for (int k0 = 0; k0 < 960; k0 += 32) {
        glds16(ga + k0,       lA);
        glds16(ga + k0 + a64, lA + 4096);
        glds16(gb + k0,       lB);
        __syncthreads();
        bf16x8 af[4], bb[2];
#pragma unroll
        for (int m = 0; m < 4; ++m)
            af[m] = *(const bf16x8*)(As + ((wr + (m << 4) + lr) << 5) + lk);
#pragma unroll
        for (int n = 0; n < 2; ++n)
            bb[n] = *(const bf16x8*)(Bs + ((wc + (n << 4) + lr) << 5) + lk);
#pragma unroll
        for (int m = 0; m < 4; ++m)
#pragma unroll
            for (int n = 0; n < 2; ++n)
                acc[m][n] = __builtin_amdgcn_mfma_f32_16x16x32_bf16(af[m], bb[n], acc[m][n], 0, 0, 0);
        __syncthreads();
    }

    const int rb  = wr + ((l >> 4) << 2);
    const int cbl = wc + lr;
#pragma unroll
    for (int m = 0; m < 4; ++m)
#pragma unroll
        for (int n = 0; n < 2; ++n)
#pragma unroll
            for (int j = 0; j < 4; ++j) {
                u16 hn = f2bf(acc[m][n][j]);
                int rl = rb + (m << 4) + j;
                int cl = cbl + (n << 4);
                long ro = (long)(i0 + rl) * 512 + j0 + cl;
                float dv = bf2f(hn);
                if (!it0) dv -= bf2f(outR[ro]);
                outR[ro] = hn;
                dh[(long)(i0 + rl) * 256 + j0 + cl] = f2bf(dv);
                Tt[cl][rl] = hn;
            }
    __syncthreads();
#pragma unroll
    for (int p = 0; p < 4; ++p) {
        int id = p * 256 + t;
        int jj = id >> 4, ch = id & 15;
        uint4 v = *(const uint4*)&Tt[jj][ch << 3];
        *(uint4*)(T + (long)(jj + j0) * 1280 + i0 + (ch << 3)) = v;
    }
}

// ---------------- fused MFMA GEMM, 128x64 tile, bf16-out; 1D grid, XCD-swizzled ----------------
__global__ __launch_bounds__(256)
void k_gbf(int nwg, int ny,
           const u16* __restrict__ A, int lda, long sA, int K,
           const u16* __restrict__ B, int ldb, long sB,
           u16* __restrict__ outR, int ldR, long sR,
           u16* __restrict__ outR2, int ldR2, long sR2,
           u16* __restrict__ outT1, int ldT1, long sT1,
           u16* __restrict__ outT2, int ldT2, long sT2, int jSplit) {
    int xb, yb, z;
    xcdmap(nwg, 8, xb, yb, z);
    (void)ny;
    A    += (long)z * sA;
    B    += (long)z * sB;
    outR += (long)z * sR;
    if (outR2) outR2 += (long)z * sR2;
    const int i0 = xb * 128, j0 = yb * 64;
    u16* T; int ldT; long sT; int jloc;
    if (j0 < jSplit) { T = outT1; ldT = ldT1; sT = sT1; jloc = j0; }
    else             { T = outT2; ldT = ldT2; sT = sT2; jloc = j0 - jSplit; }
    T += (long)z * sT;

    __shared__ u16 As[128 * 32];
    __shared__ u16 Bs[64 * 32];
    __shared__ u16 Tt[64][136];
    const int t = threadIdx.x, w = t >> 6, l = t & 63;
    const int wr = (w >> 1) << 6, wc = (w & 1) << 5;
    const int lr = l & 15, lk = (l >> 4) << 3;
    f32x4 acc[4][2] = {};

    const u16* ga = A + (long)(i0 + (t >> 2)) * lda + ((t & 3) << 3);
    const u16* gb = B + (long)(j0 + (t >> 2)) * ldb + ((t & 3) << 3);
    const long a64 = (long)lda << 6;
    char* lA = (char*)As + (w << 10);
    char* lB = (char*)Bs + (w << 10);

    for (int k0 = 0; k0 < K; k0 += 32) {
        glds16(ga + k0,       lA);
        glds16(ga + k0 + a64, lA + 4096);
        glds16(gb + k0,       lB);
        __syncthreads();
        bf16x8 af[4], bb[2];
#pragma unroll
        for (int m = 0; m < 4; ++m)
            af[m] = *(const bf16x8*)(As + ((wr + (m << 4) + lr) << 5) + lk);
#pragma unroll
        for (int n = 0; n < 2; ++n)
            bb[n] = *(const bf16x8*)(Bs + ((wc + (n << 4) + lr) << 5) + lk);
#pragma unroll
        for (int m = 0; m < 4; ++m)
#pragma unroll
            for (int n = 0; n < 2; ++n)
                acc[m][n] = __builtin_amdgcn_mfma_f32_16x16x32_bf16(af[m], bb[n], acc[m][n], 0, 0, 0);
        __syncthreads();
    }

    const int rb  = wr + ((l >> 4) << 2);
    const int cbl = wc + lr;
#pragma unroll
    for (int m = 0; m < 4; ++m)
#pragma unroll
        for (int n = 0; n < 2; ++n)
#pragma unroll
            for (int j = 0; j < 4; ++j) {
                u16 u = f2bf(acc[m][n][j]);
                int rl = rb + (m << 4) + j;
                int cl = cbl + (n << 4);
                outR[(long)(i0 + rl) * ldR + j0 + cl] = u;
                if (outR2) outR2[(long)(i0 + rl) * ldR2 + j0 + cl] = u;
                Tt[cl][rl] = u;
            }
    __syncthreads();
#pragma unroll
    for (int p = 0; p < 4; ++p) {
        int id = p * 256 + t;
        int jj = id >> 4, ch = id & 15;
        uint4 v = *(const uint4*)&Tt[jj][ch << 3];
        *(uint4*)(T + (long)(jloc + jj) * ldT + i0 + (ch << 3)) = v;
    }
}

// ---------------- MFMA GEMM 128x128, bf16-in, fp16-out (scoring-1); 1D grid, XCD-swizzled ----------------
__global__ __launch_bounds__(256)
void k_mf(const u16* __restrict__ A, const u16* __restrict__ B, u16* __restrict__ C,
          int K, int lda, int ldb, int ldc, long sA, long sB, long sC) {
    int xb, yb, z;
    xcdmap(512, 8, xb, yb, z);
    A += (long)z * sA;
    B += (long)z * sB;
    C += (long)z * sC;
    const int i0 = xb * 128, j0 = yb * 128;
    __shared__ u16 As[128 * 32];
    __shared__ u16 Bs[128 * 32];
    const int t = threadIdx.x, w = t >> 6, l = t & 63;
    const int wr = (w >> 1) << 6, wc = (w & 1) << 6;
    const int lr = l & 15, lk = (l >> 4) << 3;
    f32x4 acc[4][4] = {};
    const u16* ga = A + (long)(i0 + (t >> 2)) * lda + ((t & 3) << 3);
    const u16* gb = B + (long)(j0 + (t >> 2)) * ldb + ((t & 3) << 3);
    const long a64 = (long)lda << 6, b64 = (long)ldb << 6;
    char* lA = (char*)As + (w << 10);
    char* lB = (char*)Bs + (w << 10);
    for (int k0 = 0; k0 < K; k0 += 32) {
        glds16(ga + k0,       lA);
        glds16(ga + k0 + a64, lA + 4096);
        glds16(gb + k0,       lB);
        glds16(gb + k0 + b64, lB + 4096);
        __syncthreads();
        bf16x8 af[4], bfr[4];
#pragma unroll
        for (int m = 0; m < 4; ++m)
            af[m] = *(const bf16x8*)(As + ((wr + (m << 4) + lr) << 5) + lk);
#pragma unroll
        for (int n = 0; n < 4; ++n)
            bfr[n] = *(const bf16x8*)(Bs + ((wc + (n << 4) + lr) << 5) + lk);
#pragma unroll
        for (int m = 0; m < 4; ++m)
#pragma unroll
            for (int n = 0; n < 4; ++n)
                acc[m][n] = __builtin_amdgcn_mfma_f32_16x16x32_bf16(af[m], bfr[n], acc[m][n], 0, 0, 0);
        __syncthreads();
    }
    const int rb = i0 + wr + ((l >> 4) << 2);
    const int cb = j0 + wc + lr;
#pragma unroll
    for (int m = 0; m < 4; ++m)
#pragma unroll
        for (int n = 0; n < 4; ++n)
#pragma unroll
            for (int j = 0; j < 4; ++j)
                C[(long)(rb + (m << 4) + j) * ldc + cb + (n << 4)] = f2h(acc[m][n][j]);
}

// ---------------- scoring-2: Sf(fp16) += dH @ V^T  (K=256); 1D grid, XCD-swizzled ----------------
__global__ __launch_bounds__(256)
void k_mfa(const u16* __restrict__ DH, const u16* __restrict__ KVQ, u16* __restrict__ C) {
    int xb, yb, z;
    xcdmap(512, 8, xb, yb, z);
    const u16* A = DH + (long)z * sDH;
    const u16* B = KVQ + 256 + (long)z * sKVQ;   // V rows
    u16* Cc = C + (long)z * sS2;
    const int i0 = xb * 128, j0 = yb * 128;
    __shared__ u16 As[128 * 32];
    __shared__ u16 Bs[128 * 32];
    const int t = threadIdx.x, w = t >> 6, l = t & 63;
    const int wr = (w >> 1) << 6, wc = (w & 1) << 6;
    const int lr = l & 15, lk = (l >> 4) << 3;
    f32x4 acc[4][4] = {};
    const u16* ga = A + (long)(i0 + (t >> 2)) * 256 + ((t & 3) << 3);
    const u16* gb = B + (long)(j0 + (t >> 2)) * 768 + ((t & 3) << 3);
    const long a64 = 256L << 6, b64 = 768L << 6;
    char* lA = (char*)As + (w << 10);
    char* lB = (char*)Bs + (w << 10);
    for (int k0 = 0; k0 < 256; k0 += 32) {
        glds16(ga + k0,       lA);
        glds16(ga + k0 + a64, lA + 4096);
        glds16(gb + k0,       lB);
        glds16(gb + k0 + b64, lB + 4096);
        __syncthreads();
        bf16x8 af[4], bfr[4];
#pragma unroll
        for (int m = 0; m < 4; ++m)
            af[m] = *(const bf16x8*)(As + ((wr + (m << 4) + lr) << 5) + lk);
#pragma unroll
        for (int n = 0; n < 4; ++n)
            bfr[n] = *(const bf16x8*)(Bs + ((wc + (n << 4) + lr) << 5) + lk);
#pragma unroll
        for (int m = 0; m < 4; ++m)
#pragma unroll
            for (int n = 0; n < 4; ++n)
                acc[m][n] = __builtin_amdgcn_mfma_f32_16x16x32_bf16(af[m], bfr[n], acc[m][n], 0, 0, 0);
        __syncthreads();
    }
    const int rb = i0 + wr + ((l >> 4) << 2);
    const int cb = j0 + wc + lr;
#pragma unroll
    for (int m = 0; m < 4; ++m)
#pragma unroll
        for (int n = 0; n < 4; ++n)
#pragma unroll
            for (int j = 0; j < 4; ++j) {
                long off = (long)(rb + (m << 4) + j) * 1024 + cb + (n << 4);
                Cc[off] = f2h(h2f(Cc[off]) + acc[m][n][j]);
            }
}

// ---------------- fused softmax + S write (+ optional S^T); rows < 960 only; XCD-swizzled ----------------
template<bool WRT>
__global__ __launch_bounds__(256)
void k_smtr(const u16* __restrict__ Sf, u16* __restrict__ SXp, u16* __restrict__ STXp,
            const int* __restrict__ padf) {
    int bx, yb, b;
    xcdmap(960, 120, bx, yb, b);
    (void)yb;
    const int t = threadIdx.x;
    const int r = t >> 5, cg = t & 31;
    __shared__ u16   T8[8][1028];
    __shared__ float padd[1024];
    const int r0 = bx * 8;
    const int row = r0 + r;
    const int* pr = padf + b * 1024;
#pragma unroll
    for (int k = 0; k < 4; ++k)
        padd[t * 4 + k] = pr[t * 4 + k] ? -9999.0f : 0.0f;
    __syncthreads();
    const float prow = pr[row] ? -9999.0f : 0.0f;
    const u16* src = Sf + ((long)(b * 1024 + row)) * 1024;

    float e[32];
    float m = -3.0e38f;
#pragma unroll
    for (int q = 0; q < 8; ++q) {
        int c = cg * 4 + q * 128;
        ushort4 v = *(const ushort4*)(src + c);
#pragma unroll
        for (int j = 0; j < 4; ++j) {
            float x = (h2f((&v.x)[j]) + fminf(prow, padd[c + j])) * 0.0625f;
            e[q * 4 + j] = x;
            m = fmaxf(m, x);
        }
    }
#pragma unroll
    for (int o = 1; o < 32; o <<= 1) m = fmaxf(m, __shfl_xor(m, o));

    float s = 0.f;
#pragma unroll
    for (int i = 0; i < 32; ++i) { e[i] = expf(e[i] - m); s += e[i]; }
#pragma unroll
    for (int o = 1; o < 32; o <<= 1) s += __shfl_xor(s, o);
    const float inv = 1.0f / s;

    u16* orow = SXp + ((long)(b * 1024 + row)) * 1280 + 256;
#pragma unroll
    for (int q = 0; q < 8; ++q) {
        int c = cg * 4 + q * 128;
        ushort4 o4;
#pragma unroll
        for (int j = 0; j < 4; ++j)
            (&o4.x)[j] = (fminf(prow, padd[c + j]) < 0.f) ? (u16)0 : f2bf(e[q * 4 + j] * inv);
        *(ushort4*)(orow + c) = o4;
        if (WRT) *(ushort4*)&T8[r][c] = o4;
    }
    if (WRT) {
        __syncthreads();
#pragma unroll
        for (int p = 0; p < 4; ++p) {
            int c = t + p * 256;
            u16 tmp[8];
#pragma unroll
            for (int rr = 0; rr < 8; ++rr) tmp[rr] = T8[rr][c];
            *(uint4*)(STXp + ((long)(b * 1024 + c)) * 1280 + 256 + r0) = *(uint4*)&tmp[0];
        }
    }
}

// ---------------- masked-row Xm: [512,768]x[768,256] GEMM, indirect A rows via midx ----------------
__global__ __launch_bounds__(256)
void k_xmr(const u16* __restrict__ KVQ, const u16* __restrict__ W3T,
           const int* __restrict__ midx, const float* __restrict__ PE,
           u16* __restrict__ SXp, u16* __restrict__ STXp, u16* __restrict__ XRb, int last) {
    const int i0 = blockIdx.x * 128, j0 = blockIdx.y * 64;
    __shared__ u16 As[128 * 32];
    __shared__ u16 Bs[64 * 32];
    const int t = threadIdx.x, w = t >> 6, l = t & 63;
    const int wr = (w >> 1) << 6, wc = (w & 1) << 5;
    const int lr = l & 15, lk = (l >> 4) << 3;
    f32x4 acc[4][2] = {};
    const int r1 = i0 + (t >> 2);
    const u16* ga1 = KVQ + (long)midx[r1]      * 768 + ((t & 3) << 3);
    const u16* ga2 = KVQ + (long)midx[r1 + 64] * 768 + ((t & 3) << 3);
    const u16* gb  = W3T + (long)(j0 + (t >> 2)) * 768 + ((t & 3) << 3);
    char* lA = (char*)As + (w << 10);
    char* lB = (char*)Bs + (w << 10);
    for (int k0 = 0; k0 < 768; k0 += 32) {
        glds16(ga1 + k0, lA);
        glds16(ga2 + k0, lA + 4096);
        glds16(gb  + k0, lB);
        __syncthreads();
        bf16x8 af[4], bb[2];
#pragma unroll
        for (int m = 0; m < 4; ++m)
            af[m] = *(const bf16x8*)(As + ((wr + (m << 4) + lr) << 5) + lk);
#pragma unroll
        for (int n = 0; n < 2; ++n)
            bb[n] = *(const bf16x8*)(Bs + ((wc + (n << 4) + lr) << 5) + lk);
#pragma unroll
        for (int m = 0; m < 4; ++m)
#pragma unroll
            for (int n = 0; n < 2; ++n)
                acc[m][n] = __builtin_amdgcn_mfma_f32_16x16x32_bf16(af[m], bb[n], acc[m][n], 0, 0, 0);
        __syncthreads();
    }
    const int rb = wr + ((l >> 4) << 2);
    const int cb = wc + lr;
#pragma unroll
    for (int m = 0; m < 4; ++m)
#pragma unroll
        for (int n = 0; n < 2; ++n)
#pragma unroll
            for (int j = 0; j < 4; ++j) {
                int row = i0 + rb + (m << 4) + j;
                int col = j0 + cb + (n << 4);
                if (last) {
                    XRb[(long)row * 256 + col] = f2bf(acc[m][n][j]);
                } else {
                    int gr  = midx[row];
                    u16 xp = f2bf(acc[m][n][j] + PE[(long)(gr & 1023) * 256 + col]);
                    long oo = (long)gr * 1280 + col;
                    SXp[oo] = xp; STXp[oo] = xp;
                }
            }
}

// ---------------- logits GEMM: XRb bf16 @ embB bf16 -> fp32 out ----------------
__global__ __launch_bounds__(256)
void k_mfl(const u16* __restrict__ XRb, const u16* __restrict__ embB, float* __restrict__ C) {
    const int bid = blockIdx.x;
    const int by = bid % 500, bx = bid / 500;    // B-panel siblings 500 apart (L2 grouping)
    const int i0 = bx * 128, j0 = by * 64;
    __shared__ u16 As[128 * 32];
    __shared__ u16 Bs[64 * 32];
    const int t = threadIdx.x, w = t >> 6, l = t & 63;
    const int wr = (w >> 1) << 6, wc = (w & 1) << 5;
    const int lr = l & 15, lk = (l >> 4) << 3;
    f32x4 acc[4][2] = {};
    const u16* ga = XRb  + (long)(i0 + (t >> 2)) * 256 + ((t & 3) << 3);
    const u16* gb = embB + (long)(j0 + (t >> 2)) * 256 + ((t & 3) << 3);
    char* lA = (char*)As + (w << 10);
    char* lB = (char*)Bs + (w << 10);
    for (int k0 = 0; k0 < 256; k0 += 32) {
        glds16(ga + k0,            lA);
        glds16(ga + k0 + 64 * 256, lA + 4096);
        glds16(gb + k0,            lB);
        __syncthreads();
        bf16x8 af[4], bb[2];
#pragma unroll
        for (int m = 0; m < 4; ++m)
            af[m] = *(const bf16x8*)(As + ((wr + (m << 4) + lr) << 5) + lk);
#pragma unroll
        for (int n = 0; n < 2; ++n)
            bb[n] = *(const bf16x8*)(Bs + ((wc + (n << 4) + lr) << 5) + lk);
#pragma unroll
        for (int m = 0; m < 4; ++m)
#pragma unroll
            for (int n = 0; n < 2; ++n)
                acc[m][n] = __builtin_amdgcn_mfma_f32_16x16x32_bf16(af[m], bb[n], acc[m][n], 0, 0, 0);
        __syncthreads();
    }
    const int rb = i0 + wr + ((l >> 4) << 2);
    const int cb = j0 + wc + lr;
#pragma unroll
    for (int m = 0; m < 4; ++m)
#pragma unroll
        for (int n = 0; n < 2; ++n)
#pragma unroll
            for (int j = 0; j < 4; ++j)
                C[(long)(rb + (m << 4) + j) * 32000 + cb + (n << 4)] = acc[m][n][j];
}

// ---------------- launcher ----------------
extern "C" void kernel_launch(void* const* d_in, const int* in_sizes, int n_in,
                              void* d_out, int out_size, void* d_ws, size_t ws_size,
                              hipStream_t stream) {
    (void)in_sizes; (void)n_in; (void)out_size; (void)ws_size;
    const int*   ix   = (const int*)d_in[0];
    const int*   midx = (const int*)d_in[1];
    const float* emb  = (const float*)d_in[2];
    const float* Wq   = (const float*)d_in[3];
    const float* Wk   = (const float*)d_in[4];
    const float* Wv   = (const float*)d_in[5];

    char* base = (char*)d_ws;
    u16*   embB = (u16*)(base + B_EMB);
    u16*   Sf   = (u16*)(base + B_SF);
    u16*   SXp  = (u16*)(base + B_SXP);
    u16*   STXp = (u16*)(base + B_STXP);
    u16*   QHb  = (u16*)(base + B_QH);
    u16*   KVQ  = (u16*)(base + B_KVQ);
    u16*   BQ   = (u16*)(base + B_BQ);
    u16*   BKV  = (u16*)(base + B_BKV);
    u16*   VTb  = (u16*)(base + B_VT);
    u16*   W3T  = (u16*)(base + B_W3T);
    u16*   XRb  = (u16*)(base + B_XRB);
    float* PEf  = (float*)(base + B_PE);
    int*   padf  = (int*)(base + B_PAD);
    int*   maskf = (int*)(base + B_MSK);
    u16*   DH   = (u16*)(base + B_DH);
    float* out  = (float*)d_out;

    k_setup<<<10080, 256, 0, stream>>>(PEf, ix, padf, maskf, Wq, Wk, Wv, emb, base);
    k_embx <<<2048, 256, 0, stream>>>(ix, emb, PEf, SXp, STXp);

    const int JBIG = 1 << 30;

    for (int it = 0; it < 3; ++it) {
        // K=1216 trims the structurally-zero S cols [960,1024); 256 at iter 0 (S==0)
        const int KU = it ? 1216 : 256;
        // merged Q1 + KV1 (768 blocks, batch z -> XCD z)
        k_gupd<<<768, 256, 0, stream>>>(SXp, STXp, BQ, BKV, QHb, KVQ, VTb, KU);
        // scoring-1 = [Q|H_prev][K|V]^T (fp16 out; H=0 at it0 -> K=256)
        k_mf<<<512, 256, 0, stream>>>(QHb, KVQ, Sf, it ? 512 : 256, 512, 768, 1024, sQH, sKVQ, sS2);
        k_smtr<false><<<960, 256, 0, stream>>>(Sf, SXp, STXp, padf);   // S1: S^T write is dead
        // H = S1 V (K=960) + dH = H_new - H_prev; H^T -> BKV rows 256:512 cols 256:
        k_gbh<<<256, 256, 0, stream>>>(SXp, VTb, QHb, BKV, DH, (it == 0) ? 1 : 0);
        // scoring-2 incremental: Sf += dH V^T (K=256)
        k_mfa<<<512, 256, 0, stream>>>(DH, KVQ, Sf);
        k_smtr<true><<<960, 256, 0, stream>>>(Sf, SXp, STXp, padf);
        // [K|V] again (new S^T, new H^T, old Q^T)
        k_gbf<<<512, 256, 0, stream>>>(512, 8,
                                       STXp, 1280, sSX, 1216, BKV, 1280, sBKV,
                                       KVQ, 768, sKVQ, nullptr, 0, 0,
                                       BQ + 256, 1280, sBQ, VTb, 1024, sVT, 256);
        // Q again (new S, new K^T from KV2); Q also -> KVQ[:,512:768] for Xm
        k_gbf<<<256, 256, 0, stream>>>(256, 4,
                                       SXp, 1280, sSX, 1216, BQ, 1280, sBQ,
                                       QHb, 512, sQH, KVQ + 512, 768, sKVQ,
                                       BKV + 256, 1280, sBKV, BKV + 256, 1280, sBKV, JBIG);
        // Xm at masked rows: it<2 -> Xp refresh; it==2 -> XRb for logits
        k_xmr<<<dim3(4, 4, 1), 256, 0, stream>>>(KVQ, W3T, midx, PEf, SXp, STXp, XRb,
                                                 (it == 2) ? 1 : 0);
    }
    // logits = XRb @ embB^T
    k_mfl<<<2000, 256, 0, stream>>>(XRb, embB, out);
}

// Round 18
// 546.144 us; speedup vs baseline: 1.0030x; 1.0030x over previous
//
#include <hip/hip_runtime.h>
#include <hip/hip_bf16.h>
#include <hip/hip_fp16.h>

typedef __attribute__((ext_vector_type(8))) short bf16x8;
typedef __attribute__((ext_vector_type(4))) float f32x4;
typedef unsigned short u16;

static __device__ __forceinline__ u16 f2bf(float f) {
    union { float f; unsigned int i; } c; c.f = f;
    unsigned int r = c.i + 0x7fffu + ((c.i >> 16) & 1u);
    return (u16)(r >> 16);
}
static __device__ __forceinline__ float bf2f(u16 u) {
    union { unsigned int i; float f; } c; c.i = ((unsigned int)u) << 16; return c.f;
}
static __device__ __forceinline__ u16 f2h(float f) {
    __half h = __float2half(f);
    return *(u16*)&h;
}
static __device__ __forceinline__ float h2f(u16 u) {
    __half h = *(__half*)&u;
    return __half2float(h);
}

#define AS1(p) ((const __attribute__((address_space(1))) void*)(p))
#define AS3(p) ((__attribute__((address_space(3))) void*)(p))
static __device__ __forceinline__ void glds16(const void* g, void* l) {
    __builtin_amdgcn_global_load_lds(AS1(g), AS3(l), 16, 0, 0);
}

// XCD-coherent swizzle: 1D grid, nwg%8==0, nwg/8 == blocks per batch.
static __device__ __forceinline__ void xcdmap(int nwg, int nx, int& x, int& y, int& z) {
    const int lin = blockIdx.x;
    const int per = nwg >> 3;
    const int swz = (lin & 7) * per + (lin >> 3);
    z = swz / per;                 // == lin & 7
    const int rem = swz - z * per;
    x = rem % nx;
    y = rem / nx;
}

// ---------------- workspace layout (byte offsets) ----------------
static constexpr long B_EMB  = 0;                       // bf16 embB [32000,256]
static constexpr long B_SF   = 16777216;                // fp16 scores [8,1024,1024]
static constexpr long B_SXP  = B_SF   + 33554432;       // bf16 [Xp|S]   [8,1024,1280]
static constexpr long B_STXP = B_SXP  + 20971520;       // bf16 [Xp|S^T] [8,1024,1280]
static constexpr long B_QH   = B_STXP + 20971520;       // bf16 [Q|H] [8,1024,512]
static constexpr long B_KVQ  = B_QH   + 8388608;        // bf16 [K|V|Q] [8,1024,768]
static constexpr long B_BQ   = B_KVQ  + 12582912;       // bf16 [Wq|K^T] [8,256,1280]
static constexpr long B_BKV  = B_BQ   + 5242880;        // bf16 [Wk|Q^T ; Wv|H^T] [8,512,1280]
static constexpr long B_VT   = B_BKV  + 10485760;       // bf16 V^T [8,256,1024]
static constexpr long B_W3T  = B_VT   + 4194304;        // bf16 [Wk^T|Wv^T|Wq^T] [256,768]
static constexpr long B_XRB  = B_W3T  + 393216;         // bf16 Xm masked rows [512,256]
static constexpr long B_PE   = B_XRB  + 262144;         // fp32 PE [1024,256]
static constexpr long B_PAD  = B_PE   + 1048576;        // int pad flags
static constexpr long B_MSK  = B_PAD  + 32768;          // int mask flags
static constexpr long B_DH   = B_MSK  + 32768;          // bf16 dH [8,1024,256]

static constexpr long sSX  = 1024L * 1280;
static constexpr long sQH  = 1024L * 512;
static constexpr long sKVQ = 1024L * 768;
static constexpr long sBQ  = 256L * 1280;
static constexpr long sBKV = 512L * 1280;
static constexpr long sVT  = 256L * 1024;
static constexpr long sS2  = 1024L * 1024;
static constexpr long sDH  = 1024L * 256;

// ---------------- setup: PE + flags + weight converts + emb->bf16 in ONE launch ----------------
__global__ __launch_bounds__(256) void k_setup(float* __restrict__ PE, const int* __restrict__ ix,
                                               int* __restrict__ padf, int* __restrict__ maskf,
                                               const float* __restrict__ Wq, const float* __restrict__ Wk,
                                               const float* __restrict__ Wv, const float* __restrict__ emb,
                                               char* __restrict__ base) {
    __shared__ u16 tile[32][33];
    const int bid = blockIdx.x;
    if (bid < 512) {
        int g = bid * 256 + threadIdx.x;
        int p = g >> 7, j = g & 127;
        float di   = (float)j * (1.0f / 128.0f);
        float freq = powf(10000.0f, -di);
        float ang  = (float)p * freq;
        PE[(long)p * 256 + j]       = sinf(ang);
        PE[(long)p * 256 + j + 128] = cosf(ang);
        return;
    }
    if (bid < 544) {
        int g = (bid - 512) * 256 + threadIdx.x;
        int tok = ix[g];
        padf[g]  = (tok == 0) ? 1 : 0;
        maskf[g] = (tok == 1) ? 1 : 0;
        return;
    }
    if (bid < 2080) {
        const int idx = bid - 544;
        const int bz = idx >> 6, rem = idx & 63;
        const int bx = rem >> 3, by = rem & 7;
        const int ws = bz >> 3, rb8 = bz & 7;
        const float* W; u16 *rep, *T; long repStride;
        if (ws == 0)      { W = Wk; rep = (u16*)(base + B_BKV);               T = (u16*)(base + B_W3T);       repStride = sBKV; }
        else if (ws == 1) { W = Wv; rep = (u16*)(base + B_BKV) + 256L * 1280; T = (u16*)(base + B_W3T) + 256; repStride = sBKV; }
        else              { W = Wq; rep = (u16*)(base + B_BQ);                T = (u16*)(base + B_W3T) + 512; repStride = sBQ; }
        rep += (long)rb8 * repStride;
        const int tx = threadIdx.x & 31, ty = threadIdx.x >> 5;
#pragma unroll
        for (int rr = 0; rr < 32; rr += 8) {
            int r = bx * 32 + ty + rr, c = by * 32 + tx;
            u16 u = f2bf(W[(long)r * 256 + c]);
            rep[(long)r * 1280 + c] = u;
            if (rb8 == 0) tile[ty + rr][tx] = u;
        }
        if (rb8 == 0) {
            __syncthreads();
#pragma unroll
            for (int rr = 0; rr < 32; rr += 8)
                T[(long)(by * 32 + ty + rr) * 768 + bx * 32 + tx] = tile[tx][ty + rr];
        }
        return;
    }
    // emb -> bf16: bid in [2080, 10080)
    long e = ((long)(bid - 2080) * 256 + threadIdx.x) * 4;
    float4 v = *(const float4*)(emb + e);
    ushort4 o;
    o.x = f2bf(v.x); o.y = f2bf(v.y); o.z = f2bf(v.z); o.w = f2bf(v.w);
    *(ushort4*)((u16*)(base + B_EMB) + e) = o;
}

// ---------------- fused embed + Xp ----------------
__global__ __launch_bounds__(256) void k_embx(const int* __restrict__ ix, const float* __restrict__ emb,
                                              const float* __restrict__ PE,
                                              u16* __restrict__ SXp, u16* __restrict__ STXp) {
    int g = blockIdx.x * 256 + threadIdx.x;
    long e = (long)g * 4;
    long bn = e >> 8;
    int i = (int)(bn & 1023), c = (int)(e & 255);
    int tok = ix[bn];
    float4 v;
    if (tok == 1) v = make_float4(0.f, 0.f, 0.f, 0.f);
    else          v = *(const float4*)(emb + (long)tok * 256 + c);
    float4 p = *(const float4*)(PE + (long)i * 256 + c);
    ushort4 o;
    o.x = f2bf(v.x + p.x); o.y = f2bf(v.y + p.y);
    o.z = f2bf(v.z + p.z); o.w = f2bf(v.w + p.w);
    long oo = bn * 1280 + c;
    *(ushort4*)(SXp + oo)  = o;
    *(ushort4*)(STXp + oo) = o;
}

// ---------------- merged Q1 + KV1 update (one 1D launch, XCD-swizzled: batch z -> XCD z) ----------------
__global__ __launch_bounds__(256)
void k_gupd(const u16* __restrict__ SXp, const u16* __restrict__ STXp,
            u16* __restrict__ BQ, u16* __restrict__ BKV,
            u16* __restrict__ QHb, u16* __restrict__ KVQ, u16* __restrict__ VTb, int K) {
    int xb, y, z;
    xcdmap(768, 8, xb, y, z);
    const int i0 = xb * 128;
    const u16 *A, *B;
    u16 *outR, *T;
    int j0, ldR, ldT, jloc;
    if (y < 4) {
        j0 = y << 6;
        A = SXp + (long)z * sSX;  B = BQ + (long)z * sBQ;
        outR  = QHb + (long)z * sQH;          ldR = 512;
        T = BKV + 256 + (long)z * sBKV;       ldT = 1280; jloc = j0;
    } else {
        j0 = (y - 4) << 6;
        A = STXp + (long)z * sSX;  B = BKV + (long)z * sBKV;
        outR  = KVQ + (long)z * sKVQ;         ldR = 768;
        if (j0 < 256) { T = BQ + 256 + (long)z * sBQ; ldT = 1280; jloc = j0; }
        else          { T = VTb + (long)z * sVT;      ldT = 1024; jloc = j0 - 256; }
    }

    __shared__ u16 As[128 * 32];
    __shared__ u16 Bs[64 * 32];
    __shared__ u16 Tt[64][136];
    const int t = threadIdx.x, w = t >> 6, l = t & 63;
    const int wr = (w >> 1) << 6, wc = (w & 1) << 5;
    const int lr = l & 15, lk = (l >> 4) << 3;
    f32x4 acc[4][2] = {};

    const u16* ga = A + (long)(i0 + (t >> 2)) * 1280 + ((t & 3) << 3);
    const u16* gb = B + (long)(j0 + (t >> 2)) * 1280 + ((t & 3) << 3);
    const long a64 = 1280L << 6;
    char* lA = (char*)As + (w << 10);
    char* lB = (char*)Bs + (w << 10);

    for (int k0 = 0; k0 < K; k0 += 32) {
        glds16(ga + k0,       lA);
        glds16(ga + k0 + a64, lA + 4096);
        glds16(gb + k0,       lB);
        __syncthreads();
        bf16x8 af[4], bb[2];
#pragma unroll
        for (int m = 0; m < 4; ++m)
            af[m] = *(const bf16x8*)(As + ((wr + (m << 4) + lr) << 5) + lk);
#pragma unroll
        for (int n = 0; n < 2; ++n)
            bb[n] = *(const bf16x8*)(Bs + ((wc + (n << 4) + lr) << 5) + lk);
#pragma unroll
        for (int m = 0; m < 4; ++m)
#pragma unroll
            for (int n = 0; n < 2; ++n)
                acc[m][n] = __builtin_amdgcn_mfma_f32_16x16x32_bf16(af[m], bb[n], acc[m][n], 0, 0, 0);
        __syncthreads();
    }

    const int rb  = wr + ((l >> 4) << 2);
    const int cbl = wc + lr;
#pragma unroll
    for (int m = 0; m < 4; ++m)
#pragma unroll
        for (int n = 0; n < 2; ++n)
#pragma unroll
            for (int j = 0; j < 4; ++j) {
                u16 u = f2bf(acc[m][n][j]);
                int rl = rb + (m << 4) + j;
                int cl = cbl + (n << 4);
                outR[(long)(i0 + rl) * ldR + j0 + cl] = u;
                Tt[cl][rl] = u;
            }
    __syncthreads();
#pragma unroll
    for (int p = 0; p < 4; ++p) {
        int id = p * 256 + t;
        int jj = id >> 4, ch = id & 15;
        uint4 v = *(const uint4*)&Tt[jj][ch << 3];
        *(uint4*)(T + (long)(jloc + jj) * ldT + i0 + (ch << 3)) = v;
    }
}

// ---------------- H-update: H = S1 V (K=960) + dH emission ----------------
__global__ __launch_bounds__(256)
void k_gbh(const u16* __restrict__ SXp, const u16* __restrict__ VTb,
           u16* __restrict__ QHb, u16* __restrict__ BKV, u16* __restrict__ DH, int it0) {
    int xb, yb, z;
    xcdmap(256, 8, xb, yb, z);
    const u16* A = SXp + 256 + (long)z * sSX;
    const u16* B = VTb + (long)z * sVT;
    u16* outR = QHb + 256 + (long)z * sQH;
    u16* T    = BKV + 256L * 1280 + 256 + (long)z * sBKV;
    u16* dh   = DH + (long)z * sDH;
    const int i0 = xb * 128, j0 = yb * 64;

    __shared__ u16 As[128 * 32];
    __shared__ u16 Bs[64 * 32];
    __shared__ u16 Tt[64][136];
    const int t = threadIdx.x, w = t >> 6, l = t & 63;
    const int wr = (w >> 1) << 6, wc = (w & 1) << 5;
    const int lr = l & 15, lk = (l >> 4) << 3;
    f32x4 acc[4][2] = {};

    const u16* ga = A + (long)(i0 + (t >> 2)) * 1280 + ((t & 3) << 3);
    const u16* gb = B + (long)(j0 + (t >> 2)) * 1024 + ((t & 3) << 3);
    const long a64 = 1280L << 6;
    char* lA = (char*)As + (w << 10);
    char* lB = (char*)Bs + (w << 10);

    for (int k0 = 0; k0 < 960; k0 += 32) {
        glds16(ga + k0,       lA);
        glds16(ga + k0 + a64, lA + 4096);
        glds16(gb + k0,       lB);
        __syncthreads();
        bf16x8 af[4], bb[2];
#pragma unroll
        for (int m = 0; m < 4; ++m)
            af[m] = *(const bf16x8*)(As + ((wr + (m << 4) + lr) << 5) + lk);
#pragma unroll
        for (int n = 0; n < 2; ++n)
            bb[n] = *(const bf16x8*)(Bs + ((wc + (n << 4) + lr) << 5) + lk);
#pragma unroll
        for (int m = 0; m < 4; ++m)
#pragma unroll
            for (int n = 0; n < 2; ++n)
                acc[m][n] = __builtin_amdgcn_mfma_f32_16x16x32_bf16(af[m], bb[n], acc[m][n], 0, 0, 0);
        __syncthreads();
    }

    const int rb  = wr + ((l >> 4) << 2);
    const int cbl = wc + lr;
#pragma unroll
    for (int m = 0; m < 4; ++m)
#pragma unroll
        for (int n = 0; n < 2; ++n)
#pragma unroll
            for (int j = 0; j < 4; ++j) {
                u16 hn = f2bf(acc[m][n][j]);
                int rl = rb + (m << 4) + j;
                int cl = cbl + (n << 4);
                long ro = (long)(i0 + rl) * 512 + j0 + cl;
                float dv = bf2f(hn);
                if (!it0) dv -= bf2f(outR[ro]);
                outR[ro] = hn;
                dh[(long)(i0 + rl) * 256 + j0 + cl] = f2bf(dv);
                Tt[cl][rl] = hn;
            }
    __syncthreads();
#pragma unroll
    for (int p = 0; p < 4; ++p) {
        int id = p * 256 + t;
        int jj = id >> 4, ch = id & 15;
        uint4 v = *(const uint4*)&Tt[jj][ch << 3];
        *(uint4*)(T + (long)(jj + j0) * 1280 + i0 + (ch << 3)) = v;
    }
}

// ---------------- fused MFMA GEMM, 128x64 tile, bf16-out; 1D grid, XCD-swizzled ----------------
// outT1/outT2 may be nullptr: transpose epilogue skipped for tiles routed to a null dest.
__global__ __launch_bounds__(256)
void k_gbf(int nwg, int ny,
           const u16* __restrict__ A, int lda, long sA, int K,
           const u16* __restrict__ B, int ldb, long sB,
           u16* __restrict__ outR, int ldR, long sR,
           u16* __restrict__ outR2, int ldR2, long sR2,
           u16* __restrict__ outT1, int ldT1, long sT1,
           u16* __restrict__ outT2, int ldT2, long sT2, int jSplit) {
    int xb, yb, z;
    xcdmap(nwg, 8, xb, yb, z);
    (void)ny;
    A    += (long)z * sA;
    B    += (long)z * sB;
    outR += (long)z * sR;
    if (outR2) outR2 += (long)z * sR2;
    const int i0 = xb * 128, j0 = yb * 64;
    u16* T; int ldT; long sT; int jloc; bool hasT;
    if (j0 < jSplit) { T = outT1; ldT = ldT1; sT = sT1; jloc = j0;          hasT = (outT1 != nullptr); }
    else             { T = outT2; ldT = ldT2; sT = sT2; jloc = j0 - jSplit; hasT = (outT2 != nullptr); }
    if (hasT) T += (long)z * sT;

    __shared__ u16 As[128 * 32];
    __shared__ u16 Bs[64 * 32];
    __shared__ u16 Tt[64][136];
    const int t = threadIdx.x, w = t >> 6, l = t & 63;
    const int wr = (w >> 1) << 6, wc = (w & 1) << 5;
    const int lr = l & 15, lk = (l >> 4) << 3;
    f32x4 acc[4][2] = {};

    const u16* ga = A + (long)(i0 + (t >> 2)) * lda + ((t & 3) << 3);
    const u16* gb = B + (long)(j0 + (t >> 2)) * ldb + ((t & 3) << 3);
    const long a64 = (long)lda << 6;
    char* lA = (char*)As + (w << 10);
    char* lB = (char*)Bs + (w << 10);

    for (int k0 = 0; k0 < K; k0 += 32) {
        glds16(ga + k0,       lA);
        glds16(ga + k0 + a64, lA + 4096);
        glds16(gb + k0,       lB);
        __syncthreads();
        bf16x8 af[4], bb[2];
#pragma unroll
        for (int m = 0; m < 4; ++m)
            af[m] = *(const bf16x8*)(As + ((wr + (m << 4) + lr) << 5) + lk);
#pragma unroll
        for (int n = 0; n < 2; ++n)
            bb[n] = *(const bf16x8*)(Bs + ((wc + (n << 4) + lr) << 5) + lk);
#pragma unroll
        for (int m = 0; m < 4; ++m)
#pragma unroll
            for (int n = 0; n < 2; ++n)
                acc[m][n] = __builtin_amdgcn_mfma_f32_16x16x32_bf16(af[m], bb[n], acc[m][n], 0, 0, 0);
        __syncthreads();
    }

    const int rb  = wr + ((l >> 4) << 2);
    const int cbl = wc + lr;
#pragma unroll
    for (int m = 0; m < 4; ++m)
#pragma unroll
        for (int n = 0; n < 2; ++n)
#pragma unroll
            for (int j = 0; j < 4; ++j) {
                u16 u = f2bf(acc[m][n][j]);
                int rl = rb + (m << 4) + j;
                int cl = cbl + (n << 4);
                outR[(long)(i0 + rl) * ldR + j0 + cl] = u;
                if (outR2) outR2[(long)(i0 + rl) * ldR2 + j0 + cl] = u;
                if (hasT) Tt[cl][rl] = u;
            }
    if (hasT) {
        __syncthreads();
#pragma unroll
        for (int p = 0; p < 4; ++p) {
            int id = p * 256 + t;
            int jj = id >> 4, ch = id & 15;
            uint4 v = *(const uint4*)&Tt[jj][ch << 3];
            *(uint4*)(T + (long)(jloc + jj) * ldT + i0 + (ch << 3)) = v;
        }
    }
}

// ---------------- MFMA GEMM 128x128, bf16-in, fp16-out (scoring-1); 1D grid, XCD-swizzled ----------------
__global__ __launch_bounds__(256)
void k_mf(const u16* __restrict__ A, const u16* __restrict__ B, u16* __restrict__ C,
          int K, int lda, int ldb, int ldc, long sA, long sB, long sC) {
    int xb, yb, z;
    xcdmap(512, 8, xb, yb, z);
    A += (long)z * sA;
    B += (long)z * sB;
    C += (long)z * sC;
    const int i0 = xb * 128, j0 = yb * 128;
    __shared__ u16 As[128 * 32];
    __shared__ u16 Bs[128 * 32];
    const int t = threadIdx.x, w = t >> 6, l = t & 63;
    const int wr = (w >> 1) << 6, wc = (w & 1) << 6;
    const int lr = l & 15, lk = (l >> 4) << 3;
    f32x4 acc[4][4] = {};
    const u16* ga = A + (long)(i0 + (t >> 2)) * lda + ((t & 3) << 3);
    const u16* gb = B + (long)(j0 + (t >> 2)) * ldb + ((t & 3) << 3);
    const long a64 = (long)lda << 6, b64 = (long)ldb << 6;
    char* lA = (char*)As + (w << 10);
    char* lB = (char*)Bs + (w << 10);
    for (int k0 = 0; k0 < K; k0 += 32) {
        glds16(ga + k0,       lA);
        glds16(ga + k0 + a64, lA + 4096);
        glds16(gb + k0,       lB);
        glds16(gb + k0 + b64, lB + 4096);
        __syncthreads();
        bf16x8 af[4], bfr[4];
#pragma unroll
        for (int m = 0; m < 4; ++m)
            af[m] = *(const bf16x8*)(As + ((wr + (m << 4) + lr) << 5) + lk);
#pragma unroll
        for (int n = 0; n < 4; ++n)
            bfr[n] = *(const bf16x8*)(Bs + ((wc + (n << 4) + lr) << 5) + lk);
#pragma unroll
        for (int m = 0; m < 4; ++m)
#pragma unroll
            for (int n = 0; n < 4; ++n)
                acc[m][n] = __builtin_amdgcn_mfma_f32_16x16x32_bf16(af[m], bfr[n], acc[m][n], 0, 0, 0);
        __syncthreads();
    }
    const int rb = i0 + wr + ((l >> 4) << 2);
    const int cb = j0 + wc + lr;
#pragma unroll
    for (int m = 0; m < 4; ++m)
#pragma unroll
        for (int n = 0; n < 4; ++n)
#pragma unroll
            for (int j = 0; j < 4; ++j)
                C[(long)(rb + (m << 4) + j) * ldc + cb + (n << 4)] = f2h(acc[m][n][j]);
}

// ---------------- scoring-2: Sf(fp16) += dH @ V^T  (K=256); 1D grid, XCD-swizzled ----------------
__global__ __launch_bounds__(256)
void k_mfa(const u16* __restrict__ DH, const u16* __restrict__ KVQ, u16* __restrict__ C) {
    int xb, yb, z;
    xcdmap(512, 8, xb, yb, z);
    const u16* A = DH + (long)z * sDH;
    const u16* B = KVQ + 256 + (long)z * sKVQ;   // V rows
    u16* Cc = C + (long)z * sS2;
    const int i0 = xb * 128, j0 = yb * 128;
    __shared__ u16 As[128 * 32];
    __shared__ u16 Bs[128 * 32];
    const int t = threadIdx.x, w = t >> 6, l = t & 63;
    const int wr = (w >> 1) << 6, wc = (w & 1) << 6;
    const int lr = l & 15, lk = (l >> 4) << 3;
    f32x4 acc[4][4] = {};
    const u16* ga = A + (long)(i0 + (t >> 2)) * 256 + ((t & 3) << 3);
    const u16* gb = B + (long)(j0 + (t >> 2)) * 768 + ((t & 3) << 3);
    const long a64 = 256L << 6, b64 = 768L << 6;
    char* lA = (char*)As + (w << 10);
    char* lB = (char*)Bs + (w << 10);
    for (int k0 = 0; k0 < 256; k0 += 32) {
        glds16(ga + k0,       lA);
        glds16(ga + k0 + a64, lA + 4096);
        glds16(gb + k0,       lB);
        glds16(gb + k0 + b64, lB + 4096);
        __syncthreads();
        bf16x8 af[4], bfr[4];
#pragma unroll
        for (int m = 0; m < 4; ++m)
            af[m] = *(const bf16x8*)(As + ((wr + (m << 4) + lr) << 5) + lk);
#pragma unroll
        for (int n = 0; n < 4; ++n)
            bfr[n] = *(const bf16x8*)(Bs + ((wc + (n << 4) + lr) << 5) + lk);
#pragma unroll
        for (int m = 0; m < 4; ++m)
#pragma unroll
            for (int n = 0; n < 4; ++n)
                acc[m][n] = __builtin_amdgcn_mfma_f32_16x16x32_bf16(af[m], bfr[n], acc[m][n], 0, 0, 0);
        __syncthreads();
    }
    const int rb = i0 + wr + ((l >> 4) << 2);
    const int cb = j0 + wc + lr;
#pragma unroll
    for (int m = 0; m < 4; ++m)
#pragma unroll
        for (int n = 0; n < 4; ++n)
#pragma unroll
            for (int j = 0; j < 4; ++j) {
                long off = (long)(rb + (m << 4) + j) * 1024 + cb + (n << 4);
                Cc[off] = f2h(h2f(Cc[off]) + acc[m][n][j]);
            }
}

// ---------------- fused softmax + S write (+ optional S^T); rows < 960 only; XCD-swizzled ----------------
template<bool WRT>
__global__ __launch_bounds__(256)
void k_smtr(const u16* __restrict__ Sf, u16* __restrict__ SXp, u16* __restrict__ STXp,
            const int* __restrict__ padf) {
    int bx, yb, b;
    xcdmap(960, 120, bx, yb, b);
    (void)yb;
    const int t = threadIdx.x;
    const int r = t >> 5, cg = t & 31;
    __shared__ u16   T8[8][1028];
    __shared__ float padd[1024];
    const int r0 = bx * 8;
    const int row = r0 + r;
    const int* pr = padf + b * 1024;
#pragma unroll
    for (int k = 0; k < 4; ++k)
        padd[t * 4 + k] = pr[t * 4 + k] ? -9999.0f : 0.0f;
    __syncthreads();
    const float prow = pr[row] ? -9999.0f : 0.0f;
    const u16* src = Sf + ((long)(b * 1024 + row)) * 1024;

    float e[32];
    float m = -3.0e38f;
#pragma unroll
    for (int q = 0; q < 8; ++q) {
        int c = cg * 4 + q * 128;
        ushort4 v = *(const ushort4*)(src + c);
#pragma unroll
        for (int j = 0; j < 4; ++j) {
            float x = (h2f((&v.x)[j]) + fminf(prow, padd[c + j])) * 0.0625f;
            e[q * 4 + j] = x;
            m = fmaxf(m, x);
        }
    }
#pragma unroll
    for (int o = 1; o < 32; o <<= 1) m = fmaxf(m, __shfl_xor(m, o));

    float s = 0.f;
#pragma unroll
    for (int i = 0; i < 32; ++i) { e[i] = expf(e[i] - m); s += e[i]; }
#pragma unroll
    for (int o = 1; o < 32; o <<= 1) s += __shfl_xor(s, o);
    const float inv = 1.0f / s;

    u16* orow = SXp + ((long)(b * 1024 + row)) * 1280 + 256;
#pragma unroll
    for (int q = 0; q < 8; ++q) {
        int c = cg * 4 + q * 128;
        ushort4 o4;
#pragma unroll
        for (int j = 0; j < 4; ++j)
            (&o4.x)[j] = (fminf(prow, padd[c + j]) < 0.f) ? (u16)0 : f2bf(e[q * 4 + j] * inv);
        *(ushort4*)(orow + c) = o4;
        if (WRT) *(ushort4*)&T8[r][c] = o4;
    }
    if (WRT) {
        __syncthreads();
#pragma unroll
        for (int p = 0; p < 4; ++p) {
            int c = t + p * 256;
            u16 tmp[8];
#pragma unroll
            for (int rr = 0; rr < 8; ++rr) tmp[rr] = T8[rr][c];
            *(uint4*)(STXp + ((long)(b * 1024 + c)) * 1280 + 256 + r0) = *(uint4*)&tmp[0];
        }
    }
}

// ---------------- masked-row Xm: [512,768]x[768,256] GEMM, indirect A rows via midx ----------------
__global__ __launch_bounds__(256)
void k_xmr(const u16* __restrict__ KVQ, const u16* __restrict__ W3T,
           const int* __restrict__ midx, const float* __restrict__ PE,
           u16* __restrict__ SXp, u16* __restrict__ STXp, u16* __restrict__ XRb, int last) {
    const int i0 = blockIdx.x * 128, j0 = blockIdx.y * 64;
    __shared__ u16 As[128 * 32];
    __shared__ u16 Bs[64 * 32];
    const int t = threadIdx.x, w = t >> 6, l = t & 63;
    const int wr = (w >> 1) << 6, wc = (w & 1) << 5;
    const int lr = l & 15, lk = (l >> 4) << 3;
    f32x4 acc[4][2] = {};
    const int r1 = i0 + (t >> 2);
    const u16* ga1 = KVQ + (long)midx[r1]      * 768 + ((t & 3) << 3);
    const u16* ga2 = KVQ + (long)midx[r1 + 64] * 768 + ((t & 3) << 3);
    const u16* gb  = W3T + (long)(j0 + (t >> 2)) * 768 + ((t & 3) << 3);
    char* lA = (char*)As + (w << 10);
    char* lB = (char*)Bs + (w << 10);
    for (int k0 = 0; k0 < 768; k0 += 32) {
        glds16(ga1 + k0, lA);
        glds16(ga2 + k0, lA + 4096);
        glds16(gb  + k0, lB);
        __syncthreads();
        bf16x8 af[4], bb[2];
#pragma unroll
        for (int m = 0; m < 4; ++m)
            af[m] = *(const bf16x8*)(As + ((wr + (m << 4) + lr) << 5) + lk);
#pragma unroll
        for (int n = 0; n < 2; ++n)
            bb[n] = *(const bf16x8*)(Bs + ((wc + (n << 4) + lr) << 5) + lk);
#pragma unroll
        for (int m = 0; m < 4; ++m)
#pragma unroll
            for (int n = 0; n < 2; ++n)
                acc[m][n] = __builtin_amdgcn_mfma_f32_16x16x32_bf16(af[m], bb[n], acc[m][n], 0, 0, 0);
        __syncthreads();
    }
    const int rb = wr + ((l >> 4) << 2);
    const int cb = wc + lr;
#pragma unroll
    for (int m = 0; m < 4; ++m)
#pragma unroll
        for (int n = 0; n < 2; ++n)
#pragma unroll
            for (int j = 0; j < 4; ++j) {
                int row = i0 + rb + (m << 4) + j;
                int col = j0 + cb + (n << 4);
                if (last) {
                    XRb[(long)row * 256 + col] = f2bf(acc[m][n][j]);
                } else {
                    int gr  = midx[row];
                    u16 xp = f2bf(acc[m][n][j] + PE[(long)(gr & 1023) * 256 + col]);
                    long oo = (long)gr * 1280 + col;
                    SXp[oo] = xp; STXp[oo] = xp;
                }
            }
}

// ---------------- logits GEMM: XRb bf16 @ embB bf16 -> fp32 out ----------------
__global__ __launch_bounds__(256)
void k_mfl(const u16* __restrict__ XRb, const u16* __restrict__ embB, float* __restrict__ C) {
    const int bid = blockIdx.x;
    const int by = bid % 500, bx = bid / 500;    // B-panel siblings 500 apart (L2 grouping)
    const int i0 = bx * 128, j0 = by * 64;
    __shared__ u16 As[128 * 32];
    __shared__ u16 Bs[64 * 32];
    const int t = threadIdx.x, w = t >> 6, l = t & 63;
    const int wr = (w >> 1) << 6, wc = (w & 1) << 5;
    const int lr = l & 15, lk = (l >> 4) << 3;
    f32x4 acc[4][2] = {};
    const u16* ga = XRb  + (long)(i0 + (t >> 2)) * 256 + ((t & 3) << 3);
    const u16* gb = embB + (long)(j0 + (t >> 2)) * 256 + ((t & 3) << 3);
    char* lA = (char*)As + (w << 10);
    char* lB = (char*)Bs + (w << 10);
    for (int k0 = 0; k0 < 256; k0 += 32) {
        glds16(ga + k0,            lA);
        glds16(ga + k0 + 64 * 256, lA + 4096);
        glds16(gb + k0,            lB);
        __syncthreads();
        bf16x8 af[4], bb[2];
#pragma unroll
        for (int m = 0; m < 4; ++m)
            af[m] = *(const bf16x8*)(As + ((wr + (m << 4) + lr) << 5) + lk);
#pragma unroll
        for (int n = 0; n < 2; ++n)
            bb[n] = *(const bf16x8*)(Bs + ((wc + (n << 4) + lr) << 5) + lk);
#pragma unroll
        for (int m = 0; m < 4; ++m)
#pragma unroll
            for (int n = 0; n < 2; ++n)
                acc[m][n] = __builtin_amdgcn_mfma_f32_16x16x32_bf16(af[m], bb[n], acc[m][n], 0, 0, 0);
        __syncthreads();
    }
    const int rb = i0 + wr + ((l >> 4) << 2);
    const int cb = j0 + wc + lr;
#pragma unroll
    for (int m = 0; m < 4; ++m)
#pragma unroll
        for (int n = 0; n < 2; ++n)
#pragma unroll
            for (int j = 0; j < 4; ++j)
                C[(long)(rb + (m << 4) + j) * 32000 + cb + (n << 4)] = acc[m][n][j];
}

// ---------------- launcher ----------------
extern "C" void kernel_launch(void* const* d_in, const int* in_sizes, int n_in,
                              void* d_out, int out_size, void* d_ws, size_t ws_size,
                              hipStream_t stream) {
    (void)in_sizes; (void)n_in; (void)out_size; (void)ws_size;
    const int*   ix   = (const int*)d_in[0];
    const int*   midx = (const int*)d_in[1];
    const float* emb  = (const float*)d_in[2];
    const float* Wq   = (const float*)d_in[3];
    const float* Wk   = (const float*)d_in[4];
    const float* Wv   = (const float*)d_in[5];

    char* base = (char*)d_ws;
    u16*   embB = (u16*)(base + B_EMB);
    u16*   Sf   = (u16*)(base + B_SF);
    u16*   SXp  = (u16*)(base + B_SXP);
    u16*   STXp = (u16*)(base + B_STXP);
    u16*   QHb  = (u16*)(base + B_QH);
    u16*   KVQ  = (u16*)(base + B_KVQ);
    u16*   BQ   = (u16*)(base + B_BQ);
    u16*   BKV  = (u16*)(base + B_BKV);
    u16*   VTb  = (u16*)(base + B_VT);
    u16*   W3T  = (u16*)(base + B_W3T);
    u16*   XRb  = (u16*)(base + B_XRB);
    float* PEf  = (float*)(base + B_PE);
    int*   padf  = (int*)(base + B_PAD);
    int*   maskf = (int*)(base + B_MSK);
    u16*   DH   = (u16*)(base + B_DH);
    float* out  = (float*)d_out;

    k_setup<<<10080, 256, 0, stream>>>(PEf, ix, padf, maskf, Wq, Wk, Wv, emb, base);
    k_embx <<<2048, 256, 0, stream>>>(ix, emb, PEf, SXp, STXp);

    const int JBIG = 1 << 30;

    for (int it = 0; it < 3; ++it) {
        // K=1216 trims the structurally-zero S cols [960,1024); 256 at iter 0 (S==0)
        const int KU = it ? 1216 : 256;
        // merged Q1 + KV1 (768 blocks, batch z -> XCD z)
        k_gupd<<<768, 256, 0, stream>>>(SXp, STXp, BQ, BKV, QHb, KVQ, VTb, KU);
        // scoring-1 = [Q|H_prev][K|V]^T (fp16 out; H=0 at it0 -> K=256)
        k_mf<<<512, 256, 0, stream>>>(QHb, KVQ, Sf, it ? 512 : 256, 512, 768, 1024, sQH, sKVQ, sS2);
        k_smtr<false><<<960, 256, 0, stream>>>(Sf, SXp, STXp, padf);   // S1: S^T write is dead
        // H = S1 V (K=960) + dH = H_new - H_prev; H^T -> BKV rows 256:512 cols 256:
        k_gbh<<<256, 256, 0, stream>>>(SXp, VTb, QHb, BKV, DH, (it == 0) ? 1 : 0);
        // scoring-2 incremental: Sf += dH V^T (K=256)
        k_mfa<<<512, 256, 0, stream>>>(DH, KVQ, Sf);
        k_smtr<true><<<960, 256, 0, stream>>>(Sf, SXp, STXp, padf);
        // [K|V] again (new S^T, new H^T, old Q^T); V^T is ALWAYS dead here (gbh already consumed KV1's VTb)
        k_gbf<<<512, 256, 0, stream>>>(512, 8,
                                       STXp, 1280, sSX, 1216, BKV, 1280, sBKV,
                                       KVQ, 768, sKVQ, nullptr, 0, 0,
                                       BQ + 256, 1280, sBQ, nullptr, 0, 0, 256);
        // Q again (new S, new K^T from KV2); at last iter only the KVQ Q-copy is live
        if (it < 2)
            k_gbf<<<256, 256, 0, stream>>>(256, 4,
                                           SXp, 1280, sSX, 1216, BQ, 1280, sBQ,
                                           QHb, 512, sQH, KVQ + 512, 768, sKVQ,
                                           BKV + 256, 1280, sBKV, BKV + 256, 1280, sBKV, JBIG);
        else
            k_gbf<<<256, 256, 0, stream>>>(256, 4,
                                           SXp, 1280, sSX, 1216, BQ, 1280, sBQ,
                                           KVQ + 512, 768, sKVQ, nullptr, 0, 0,
                                           nullptr, 0, 0, nullptr, 0, 0, JBIG);
        // Xm at masked rows: it<2 -> Xp refresh; it==2 -> XRb for logits
        k_xmr<<<dim3(4, 4, 1), 256, 0, stream>>>(KVQ, W3T, midx, PEf, SXp, STXp, XRb,
                                                 (it == 2) ? 1 : 0);
    }
    // logits = XRb @ embB^T
    k_mfl<<<2000, 256, 0, stream>>>(XRb, embB, out);
}